// Round 1
// baseline (10716.383 us; speedup 1.0000x reference)
//
#include <hip/hip_runtime.h>

// LSTM: B=64, T=1024, IN=256, H=512, gates=2048; then Linear 512->512.
// Inputs (fp32): x, h0, c0, w_lstm[768,2048], b_lstm[2048], w_lin[512,512], b_lin[512]
// Output (fp32): y[64,1024,512] ++ h_fin[64,512] ++ c_fin[64,512]

#define BB   64
#define TT   1024
#define DIN  256
#define HH   512
#define OUTD 512
#define NBG  4            // batch groups of 16 rows
#define NCG  32           // col groups of 16 h-cols (=> 64 gate cols each)
#define YTOT (BB*TT*OUTD) // 33554432

typedef __attribute__((ext_vector_type(4))) float f32x4;
typedef __attribute__((ext_vector_type(8))) short short8;

__device__ inline short f2bf(float f) {
    unsigned u = __float_as_uint(f);
    unsigned r = u + 0x7fffu + ((u >> 16) & 1u);   // RNE
    return (short)(r >> 16);
}
__device__ inline float sigf(float x) { return 1.0f / (1.0f + __expf(-x)); }
__device__ inline float tanhfast(float x) { return 1.0f - 2.0f / (__expf(2.0f * x) + 1.0f); }

__device__ inline short8 pack8(f32x4 lo, f32x4 hi) {
    short8 a;
    a[0] = f2bf(lo[0]); a[1] = f2bf(lo[1]); a[2] = f2bf(lo[2]); a[3] = f2bf(lo[3]);
    a[4] = f2bf(hi[0]); a[5] = f2bf(hi[1]); a[6] = f2bf(hi[2]); a[7] = f2bf(hi[3]);
    return a;
}

#define MFMA(a, b, c) __builtin_amdgcn_mfma_f32_16x16x32_bf16((a), (b), (c), 0, 0, 0)

// ---------------------------------------------------------------------------
// Recurrent kernel. 128 WGs x 256 threads.
// WG (bg,cg): batch rows [bg*16, +16), h-cols [cg*16, +16) -> gate cols
// {cg*16+j, 512+.., 1024+.., 1536+..}. Wave w handles gate type w (i,g,f,o).
// Weight slice lives in registers (24 x short8 B-fragments per lane).
// Sync: per-bg monotone counter in d_ws (device-scope atomics).
// ---------------------------------------------------------------------------
__global__ __launch_bounds__(256, 1) void lstm_rec(
    const float* __restrict__ x, const float* __restrict__ h0, const float* __restrict__ c0,
    const float* __restrict__ wl, const float* __restrict__ bl,
    float* __restrict__ out, unsigned* __restrict__ cnt, unsigned short* __restrict__ hbuf)
{
    const int bid = blockIdx.x;
    const int bg  = bid >> 5;          // 0..3
    const int cg  = bid & 31;          // 0..31
    const int tid = threadIdx.x;
    const int w   = tid >> 6;          // 0..3 = gate type
    const int lane = tid & 63;
    const int nl  = lane & 15;
    const int kq  = lane >> 4;

    __shared__ float gates[4][16][17];

    // ---- Preload B fragments (weights) into registers: K=768 -> 24 k-steps.
    short8 bf[24];
    {
        const int gcol = w * HH + cg * 16 + nl;    // gate col in [0,2048)
        #pragma unroll
        for (int kk = 0; kk < 24; ++kk) {
            short8 v;
            #pragma unroll
            for (int j = 0; j < 8; ++j) {
                int k = kk * 32 + kq * 8 + j;
                v[j] = f2bf(wl[(size_t)k * 2048 + gcol]);
            }
            bf[kk] = v;
        }
    }
    const float bias = bl[w * HH + cg * 16 + nl];

    // Elementwise-phase mapping (thread-local c state).
    const int ebl   = tid >> 4;            // batch-local 0..15
    const int ej    = tid & 15;            // col-local 0..15
    const int ebrow = bg * 16 + ebl;
    const int ecol  = cg * 16 + ej;
    float creg = c0[(size_t)ebrow * HH + ecol];

    const int arow = bg * 16 + nl;         // batch row this lane loads for A-frags
    unsigned* myCnt = cnt + bg * 32;       // 128B-separated counters

    const f32x4 zero = {0.f, 0.f, 0.f, 0.f};

    for (int t = 0; t < TT; ++t) {
        f32x4 acc[4];
        acc[0] = zero; acc[1] = zero; acc[2] = zero; acc[3] = zero;

        // ---- x part: k in [0,256)
        {
            const float* xp = x + ((size_t)arow * TT + t) * DIN + kq * 8;
            #pragma unroll
            for (int kk = 0; kk < 8; ++kk) {
                f32x4 lo = *(const f32x4*)(xp + kk * 32);
                f32x4 hi = *(const f32x4*)(xp + kk * 32 + 4);
                short8 a = pack8(lo, hi);
                acc[kk & 3] = MFMA(a, bf[kk], acc[kk & 3]);
            }
        }
        // ---- h part: k in [256,768)
        if (t == 0) {
            const float* hp = h0 + (size_t)arow * HH + kq * 8;
            #pragma unroll
            for (int kk = 0; kk < 16; ++kk) {
                f32x4 lo = *(const f32x4*)(hp + kk * 32);
                f32x4 hi = *(const f32x4*)(hp + kk * 32 + 4);
                short8 a = pack8(lo, hi);
                acc[kk & 3] = MFMA(a, bf[8 + kk], acc[kk & 3]);
            }
        } else {
            const unsigned short* hp = hbuf + ((t - 1) & 1) * (BB * HH) + (size_t)arow * HH + kq * 8;
            #pragma unroll
            for (int kk = 0; kk < 16; ++kk) {
                short8 a = *(const short8*)(hp + kk * 32);
                acc[kk & 3] = MFMA(a, bf[8 + kk], acc[kk & 3]);
            }
        }

        // ---- gate tile -> LDS (C layout: row=(l>>4)*4+r, col=l&15)
        #pragma unroll
        for (int r = 0; r < 4; ++r)
            gates[w][kq * 4 + r][nl] = acc[0][r] + acc[1][r] + acc[2][r] + acc[3][r] + bias;
        __syncthreads();

        // ---- elementwise (per-thread owns one (b,hcol))
        float iv = gates[0][ebl][ej];
        float gv = gates[1][ebl][ej];
        float fv = gates[2][ebl][ej];
        float ov = gates[3][ebl][ej];
        float fs = sigf(fv + 1.0f);                 // haiku forget bias
        creg = fs * creg + sigf(iv) * tanhfast(gv);
        float hn = sigf(ov) * tanhfast(creg);

        out[((size_t)ebrow * TT + t) * OUTD + ecol] = hn;
        hbuf[(t & 1) * (BB * HH) + ebrow * HH + ecol] = (unsigned short)f2bf(hn);

        if (t == TT - 1) {
            out[YTOT + (size_t)ebrow * OUTD + ecol] = hn;               // h_fin
            out[YTOT + BB * OUTD + (size_t)ebrow * OUTD + ecol] = creg; // c_fin
        } else {
            __syncthreads();   // drain hbuf stores (vmcnt) + protect gates reuse
            if (tid == 0) {
                __hip_atomic_fetch_add(myCnt, 1u, __ATOMIC_RELEASE, __HIP_MEMORY_SCOPE_AGENT);
                const unsigned tgt = 32u * (unsigned)(t + 1);
                while (__hip_atomic_load(myCnt, __ATOMIC_RELAXED, __HIP_MEMORY_SCOPE_AGENT) < tgt)
                    __builtin_amdgcn_s_sleep(1);
                __threadfence();   // acquire: invalidate caches before reading peers' h
            }
            __syncthreads();
        }
    }
}

// ---------------------------------------------------------------------------
// w_lin -> Bt (bf16, transposed [n][k]) so B-fragments are contiguous 16B.
// ---------------------------------------------------------------------------
__global__ void conv_wlin(const float* __restrict__ wlin, unsigned short* __restrict__ Bt)
{
    const int g  = blockIdx.x * 256 + threadIdx.x;   // 32768 threads
    const int n  = g >> 6;
    const int kb = (g & 63) * 8;
    short8 v;
    #pragma unroll
    for (int j = 0; j < 8; ++j) v[j] = f2bf(wlin[(size_t)(kb + j) * OUTD + n]);
    *(short8*)(Bt + (size_t)n * OUTD + kb) = v;
}

// ---------------------------------------------------------------------------
// In-place y = h_hist @ w_lin + b_lin on d_out (32 rows per WG, row-local).
// ---------------------------------------------------------------------------
__global__ __launch_bounds__(256, 2) void out_linear(
    float* __restrict__ out, const unsigned short* __restrict__ Bt, const float* __restrict__ blin)
{
    const int r0  = blockIdx.x * 32;
    const int tid = threadIdx.x;
    const int w = tid >> 6, lane = tid & 63, nl = lane & 15, kq = lane >> 4;

    __shared__ unsigned short aLds[32][520];

    {   // stage 32 rows x 512 fp32 -> bf16 LDS
        const int row = tid >> 3;
        const int cb  = (tid & 7) * 64;
        const float* src = out + (size_t)(r0 + row) * OUTD + cb;
        #pragma unroll
        for (int c = 0; c < 64; c += 4) {
            f32x4 v = *(const f32x4*)(src + c);
            aLds[row][cb + c + 0] = (unsigned short)f2bf(v[0]);
            aLds[row][cb + c + 1] = (unsigned short)f2bf(v[1]);
            aLds[row][cb + c + 2] = (unsigned short)f2bf(v[2]);
            aLds[row][cb + c + 3] = (unsigned short)f2bf(v[3]);
        }
    }
    __syncthreads();

    const f32x4 zero = {0.f, 0.f, 0.f, 0.f};
    f32x4 acc[2][8];
    #pragma unroll
    for (int m = 0; m < 2; ++m)
        #pragma unroll
        for (int n = 0; n < 8; ++n) acc[m][n] = zero;

    #pragma unroll
    for (int kk = 0; kk < 16; ++kk) {
        short8 A0 = *(const short8*)&aLds[nl][kk * 32 + kq * 8];
        short8 A1 = *(const short8*)&aLds[16 + nl][kk * 32 + kq * 8];
        #pragma unroll
        for (int n = 0; n < 8; ++n) {
            const int nt = w * 8 + n;
            short8 Bv = *(const short8*)(Bt + (size_t)(nt * 16 + nl) * OUTD + kk * 32 + kq * 8);
            acc[0][n] = MFMA(A0, Bv, acc[0][n]);
            acc[1][n] = MFMA(A1, Bv, acc[1][n]);
        }
    }

    #pragma unroll
    for (int mt = 0; mt < 2; ++mt)
        #pragma unroll
        for (int n = 0; n < 8; ++n) {
            const int col = (w * 8 + n) * 16 + nl;
            const float bb = blin[col];
            #pragma unroll
            for (int r = 0; r < 4; ++r)
                out[(size_t)(r0 + mt * 16 + kq * 4 + r) * OUTD + col] = acc[mt][n][r] + bb;
        }
}

// ---------------------------------------------------------------------------
extern "C" void kernel_launch(void* const* d_in, const int* in_sizes, int n_in,
                              void* d_out, int out_size, void* d_ws, size_t ws_size,
                              hipStream_t stream)
{
    const float* x    = (const float*)d_in[0];
    const float* h0   = (const float*)d_in[1];
    const float* c0   = (const float*)d_in[2];
    const float* wl   = (const float*)d_in[3];
    const float* bl   = (const float*)d_in[4];
    const float* wlin = (const float*)d_in[5];
    const float* blin = (const float*)d_in[6];
    float* out = (float*)d_out;

    unsigned*       cnt  = (unsigned*)d_ws;
    unsigned short* hbuf = (unsigned short*)((char*)d_ws + 4096);               // 2*64*512*2 = 128KB
    unsigned short* Bt   = (unsigned short*)((char*)d_ws + 4096 + 2 * BB * HH * 2); // 512KB

    hipMemsetAsync(d_ws, 0, 4096, stream);                 // zero barrier counters
    conv_wlin<<<128, 256, 0, stream>>>(wlin, Bt);
    lstm_rec<<<NBG * NCG, 256, 0, stream>>>(x, h0, c0, wl, bl, out, cnt, hbuf);
    out_linear<<<(BB * TT) / 32, 256, 0, stream>>>(out, Bt, blin);
}

// Round 2
// 7049.686 us; speedup vs baseline: 1.5201x; 1.5201x over previous
//
#include <hip/hip_runtime.h>

// LSTM: B=64, T=1024, IN=256, H=512, gates=2048; then Linear 512->512.
// Inputs (fp32): x, h0, c0, w_lstm[768,2048], b_lstm[2048], w_lin[512,512], b_lin[512]
// Output (fp32): y[64,1024,512] ++ h_fin[64,512] ++ c_fin[64,512]

#define BB   64
#define TT   1024
#define DIN  256
#define HH   512
#define OUTD 512
#define NBG  4            // batch groups of 16 rows
#define NCG  32           // col groups of 16 h-cols (=> 64 gate cols each)
#define YTOT (BB*TT*OUTD) // 33554432

typedef __attribute__((ext_vector_type(4))) float f32x4;
typedef __attribute__((ext_vector_type(8))) short short8;

__device__ inline short f2bf(float f) {
    unsigned u = __float_as_uint(f);
    unsigned r = u + 0x7fffu + ((u >> 16) & 1u);   // RNE
    return (short)(r >> 16);
}
__device__ inline float sigf(float x) { return 1.0f / (1.0f + __expf(-x)); }
__device__ inline float tanhfast(float x) { return 1.0f - 2.0f / (__expf(2.0f * x) + 1.0f); }

__device__ inline short8 pack8(f32x4 lo, f32x4 hi) {
    short8 a;
    a[0] = f2bf(lo[0]); a[1] = f2bf(lo[1]); a[2] = f2bf(lo[2]); a[3] = f2bf(lo[3]);
    a[4] = f2bf(hi[0]); a[5] = f2bf(hi[1]); a[6] = f2bf(hi[2]); a[7] = f2bf(hi[3]);
    return a;
}

#define MFMA(a, b, c) __builtin_amdgcn_mfma_f32_16x16x32_bf16((a), (b), (c), 0, 0, 0)

// MALL-coherent (device-scope, per-access) primitives — no L2 flush/inv.
__device__ inline void store_h_mall(unsigned short* p, unsigned v) {
    asm volatile("global_store_short %0, %1, off sc0 sc1" :: "v"(p), "v"(v) : "memory");
}

// ---------------------------------------------------------------------------
// Recurrent kernel. 128 WGs x 256 threads.
// WG (bg,cg): batch rows [bg*16, +16), h-cols [cg*16, +16) -> gate cols
// {cg*16+j, 512+.., 1024+.., 1536+..}. Wave w handles gate type w (i,g,f,o).
// Weight slice lives in registers (24 x short8 B-fragments per lane).
// Sync: per-bg monotone counter, RELAXED agent atomics only; h exchanged via
// sc0 sc1 stores/loads (write-through to / read from MALL coherence point).
// ---------------------------------------------------------------------------
__global__ __launch_bounds__(256, 1) void lstm_rec(
    const float* __restrict__ x, const float* __restrict__ h0, const float* __restrict__ c0,
    const float* __restrict__ wl, const float* __restrict__ bl,
    float* __restrict__ out, unsigned* __restrict__ cnt, unsigned short* __restrict__ hbuf)
{
    const int bid = blockIdx.x;
    const int bg  = bid >> 5;          // 0..3
    const int cg  = bid & 31;          // 0..31
    const int tid = threadIdx.x;
    const int w   = tid >> 6;          // 0..3 = gate type
    const int lane = tid & 63;
    const int nl  = lane & 15;
    const int kq  = lane >> 4;

    __shared__ float gates[4][16][17];

    // ---- Preload B fragments (weights) into registers: K=768 -> 24 k-steps.
    short8 bf[24];
    {
        const int gcol = w * HH + cg * 16 + nl;    // gate col in [0,2048)
        #pragma unroll
        for (int kk = 0; kk < 24; ++kk) {
            short8 v;
            #pragma unroll
            for (int j = 0; j < 8; ++j) {
                int k = kk * 32 + kq * 8 + j;
                v[j] = f2bf(wl[(size_t)k * 2048 + gcol]);
            }
            bf[kk] = v;
        }
    }
    const float bias = bl[w * HH + cg * 16 + nl];

    // Elementwise-phase mapping (thread-local c state).
    const int ebl   = tid >> 4;            // batch-local 0..15
    const int ej    = tid & 15;            // col-local 0..15
    const int ebrow = bg * 16 + ebl;
    const int ecol  = cg * 16 + ej;
    float creg = c0[(size_t)ebrow * HH + ecol];

    const int arow = bg * 16 + nl;         // batch row this lane loads for A-frags
    unsigned* myCnt = cnt + bg * 32;       // 128B-separated counters

    const f32x4 zero = {0.f, 0.f, 0.f, 0.f};

    for (int t = 0; t < TT; ++t) {
        f32x4 acc[4];
        acc[0] = zero; acc[1] = zero; acc[2] = zero; acc[3] = zero;

        // ---- x part: k in [0,256)  (normal cached loads; L2 stays warm now)
        {
            const float* xp = x + ((size_t)arow * TT + t) * DIN + kq * 8;
            #pragma unroll
            for (int kk = 0; kk < 8; ++kk) {
                f32x4 lo = *(const f32x4*)(xp + kk * 32);
                f32x4 hi = *(const f32x4*)(xp + kk * 32 + 4);
                short8 a = pack8(lo, hi);
                acc[kk & 3] = MFMA(a, bf[kk], acc[kk & 3]);
            }
        }
        // ---- h part: k in [256,768)
        if (t == 0) {
            const float* hp = h0 + (size_t)arow * HH + kq * 8;
            #pragma unroll
            for (int kk = 0; kk < 16; ++kk) {
                f32x4 lo = *(const f32x4*)(hp + kk * 32);
                f32x4 hi = *(const f32x4*)(hp + kk * 32 + 4);
                short8 a = pack8(lo, hi);
                acc[kk & 3] = MFMA(a, bf[8 + kk], acc[kk & 3]);
            }
        } else {
            const unsigned short* hp = hbuf + ((t - 1) & 1) * (BB * HH) + (size_t)arow * HH + kq * 8;
            short8 ha[16];
            #pragma unroll
            for (int kk = 0; kk < 16; ++kk)
                asm volatile("global_load_dwordx4 %0, %1, off offset:%2 sc0 sc1"
                             : "=&v"(ha[kk]) : "v"(hp), "i"(kk * 64));
            asm volatile("s_waitcnt vmcnt(0)" ::: "memory");
            __builtin_amdgcn_sched_barrier(0);
            #pragma unroll
            for (int kk = 0; kk < 16; ++kk)
                acc[kk & 3] = MFMA(ha[kk], bf[8 + kk], acc[kk & 3]);
        }

        // ---- gate tile -> LDS (C layout: row=(l>>4)*4+r, col=l&15)
        #pragma unroll
        for (int r = 0; r < 4; ++r)
            gates[w][kq * 4 + r][nl] = acc[0][r] + acc[1][r] + acc[2][r] + acc[3][r] + bias;
        __syncthreads();

        // ---- elementwise (per-thread owns one (b,hcol))
        float iv = gates[0][ebl][ej];
        float gv = gates[1][ebl][ej];
        float fv = gates[2][ebl][ej];
        float ov = gates[3][ebl][ej];
        float fs = sigf(fv + 1.0f);                 // haiku forget bias
        creg = fs * creg + sigf(iv) * tanhfast(gv);
        float hn = sigf(ov) * tanhfast(creg);

        out[((size_t)ebrow * TT + t) * OUTD + ecol] = hn;
        store_h_mall(hbuf + (t & 1) * (BB * HH) + ebrow * HH + ecol, (unsigned)(unsigned short)f2bf(hn));

        if (t == TT - 1) {
            out[YTOT + (size_t)ebrow * OUTD + ecol] = hn;               // h_fin
            out[YTOT + BB * OUTD + (size_t)ebrow * OUTD + ecol] = creg; // c_fin
        } else {
            // release: own store acked at MALL, then WG-wide rendezvous
            asm volatile("s_waitcnt vmcnt(0)" ::: "memory");
            __syncthreads();   // all waves' h stores acked; protects gates reuse
            if (tid == 0) {
                __hip_atomic_fetch_add(myCnt, 1u, __ATOMIC_RELAXED, __HIP_MEMORY_SCOPE_AGENT);
                const unsigned tgt = 32u * (unsigned)(t + 1);
                while (__hip_atomic_load(myCnt, __ATOMIC_RELAXED, __HIP_MEMORY_SCOPE_AGENT) < tgt)
                    __builtin_amdgcn_s_sleep(1);
            }
            __syncthreads();
            __builtin_amdgcn_sched_barrier(0);
        }
    }
}

// ---------------------------------------------------------------------------
// w_lin -> Bt (bf16, transposed [n][k]) so B-fragments are contiguous 16B.
// ---------------------------------------------------------------------------
__global__ void conv_wlin(const float* __restrict__ wlin, unsigned short* __restrict__ Bt)
{
    const int g  = blockIdx.x * 256 + threadIdx.x;   // 32768 threads
    const int n  = g >> 6;
    const int kb = (g & 63) * 8;
    short8 v;
    #pragma unroll
    for (int j = 0; j < 8; ++j) v[j] = f2bf(wlin[(size_t)(kb + j) * OUTD + n]);
    *(short8*)(Bt + (size_t)n * OUTD + kb) = v;
}

// ---------------------------------------------------------------------------
// In-place y = h_hist @ w_lin + b_lin on d_out (32 rows per WG, row-local).
// ---------------------------------------------------------------------------
__global__ __launch_bounds__(256, 2) void out_linear(
    float* __restrict__ out, const unsigned short* __restrict__ Bt, const float* __restrict__ blin)
{
    const int r0  = blockIdx.x * 32;
    const int tid = threadIdx.x;
    const int w = tid >> 6, lane = tid & 63, nl = lane & 15, kq = lane >> 4;

    __shared__ unsigned short aLds[32][520];

    {   // stage 32 rows x 512 fp32 -> bf16 LDS
        const int row = tid >> 3;
        const int cb  = (tid & 7) * 64;
        const float* src = out + (size_t)(r0 + row) * OUTD + cb;
        #pragma unroll
        for (int c = 0; c < 64; c += 4) {
            f32x4 v = *(const f32x4*)(src + c);
            aLds[row][cb + c + 0] = (unsigned short)f2bf(v[0]);
            aLds[row][cb + c + 1] = (unsigned short)f2bf(v[1]);
            aLds[row][cb + c + 2] = (unsigned short)f2bf(v[2]);
            aLds[row][cb + c + 3] = (unsigned short)f2bf(v[3]);
        }
    }
    __syncthreads();

    const f32x4 zero = {0.f, 0.f, 0.f, 0.f};
    f32x4 acc[2][8];
    #pragma unroll
    for (int m = 0; m < 2; ++m)
        #pragma unroll
        for (int n = 0; n < 8; ++n) acc[m][n] = zero;

    #pragma unroll
    for (int kk = 0; kk < 16; ++kk) {
        short8 A0 = *(const short8*)&aLds[nl][kk * 32 + kq * 8];
        short8 A1 = *(const short8*)&aLds[16 + nl][kk * 32 + kq * 8];
        #pragma unroll
        for (int n = 0; n < 8; ++n) {
            const int nt = w * 8 + n;
            short8 Bv = *(const short8*)(Bt + (size_t)(nt * 16 + nl) * OUTD + kk * 32 + kq * 8);
            acc[0][n] = MFMA(A0, Bv, acc[0][n]);
            acc[1][n] = MFMA(A1, Bv, acc[1][n]);
        }
    }

    #pragma unroll
    for (int mt = 0; mt < 2; ++mt)
        #pragma unroll
        for (int n = 0; n < 8; ++n) {
            const int col = (w * 8 + n) * 16 + nl;
            const float bb = blin[col];
            #pragma unroll
            for (int r = 0; r < 4; ++r)
                out[(size_t)(r0 + mt * 16 + kq * 4 + r) * OUTD + col] = acc[mt][n][r] + bb;
        }
}

// ---------------------------------------------------------------------------
extern "C" void kernel_launch(void* const* d_in, const int* in_sizes, int n_in,
                              void* d_out, int out_size, void* d_ws, size_t ws_size,
                              hipStream_t stream)
{
    const float* x    = (const float*)d_in[0];
    const float* h0   = (const float*)d_in[1];
    const float* c0   = (const float*)d_in[2];
    const float* wl   = (const float*)d_in[3];
    const float* bl   = (const float*)d_in[4];
    const float* wlin = (const float*)d_in[5];
    const float* blin = (const float*)d_in[6];
    float* out = (float*)d_out;

    unsigned*       cnt  = (unsigned*)d_ws;
    unsigned short* hbuf = (unsigned short*)((char*)d_ws + 4096);               // 2*64*512*2 = 128KB
    unsigned short* Bt   = (unsigned short*)((char*)d_ws + 4096 + 2 * BB * HH * 2); // 512KB

    hipMemsetAsync(d_ws, 0, 4096, stream);                 // zero barrier counters
    conv_wlin<<<128, 256, 0, stream>>>(wlin, Bt);
    lstm_rec<<<NBG * NCG, 256, 0, stream>>>(x, h0, c0, wl, bl, out, cnt, hbuf);
    out_linear<<<(BB * TT) / 32, 256, 0, stream>>>(out, Bt, blin);
}

// Round 4
// 5663.905 us; speedup vs baseline: 1.8920x; 1.2447x over previous
//
#include <hip/hip_runtime.h>

// LSTM: B=64, T=1024, IN=256, H=512, gates=2048; then Linear 512->512.
// Inputs (fp32): x, h0, c0, w_lstm[768,2048], b_lstm[2048], w_lin[512,512], b_lin[512]
// Output (fp32): y[64,1024,512] ++ h_fin[64,512] ++ c_fin[64,512]
//
// 128 WGs: 4 batch-groups (16 rows) x 32 col-groups (16 h-cols -> 64 gate cols).
// Cross-WG h exchange + barrier through the MALL (sc0 sc1) — placement-agnostic
// (G16-safe). Barrier = per-WAVE flag stores (no atomic RMW serialization) +
// wave-parallel flag poll.

#define BB   64
#define TT   1024
#define DIN  256
#define HH   512
#define OUTD 512
#define YTOT (BB*TT*OUTD)

typedef __attribute__((ext_vector_type(4))) float f32x4;
typedef __attribute__((ext_vector_type(4))) unsigned u32x4;
typedef __attribute__((ext_vector_type(8))) short short8;

__device__ inline short f2bf(float f) {
    unsigned u = __float_as_uint(f);
    unsigned r = u + 0x7fffu + ((u >> 16) & 1u);   // RNE
    return (short)(r >> 16);
}
__device__ inline float sigf(float x) { return 1.0f / (1.0f + __expf(-x)); }
__device__ inline float tanhfast(float x) { return 1.0f - 2.0f / (__expf(2.0f * x) + 1.0f); }

__device__ inline short8 pack8(f32x4 lo, f32x4 hi) {
    short8 a;
    a[0] = f2bf(lo[0]); a[1] = f2bf(lo[1]); a[2] = f2bf(lo[2]); a[3] = f2bf(lo[3]);
    a[4] = f2bf(hi[0]); a[5] = f2bf(hi[1]); a[6] = f2bf(hi[2]); a[7] = f2bf(hi[3]);
    return a;
}

#define MFMA(a, b, c) __builtin_amdgcn_mfma_f32_16x16x32_bf16((a), (b), (c), 0, 0, 0)

// x-part of the gate GEMM for one timestep: 8 MFMAs, K=[0,256).
__device__ inline void xpart(f32x4 acc[4], const float* __restrict__ x, int arow, int t, int kq,
                             const short8* bf) {
    const float* xp = x + ((size_t)arow * TT + t) * DIN + kq * 8;
    #pragma unroll
    for (int kk = 0; kk < 8; ++kk) {
        f32x4 lo = *(const f32x4*)(xp + kk * 32);
        f32x4 hi = *(const f32x4*)(xp + kk * 32 + 4);
        acc[kk & 3] = MFMA(pack8(lo, hi), bf[kk], acc[kk & 3]);
    }
}

__global__ __launch_bounds__(256, 1) void lstm_rec(
    const float* __restrict__ x, const float* __restrict__ h0, const float* __restrict__ c0,
    const float* __restrict__ wl, const float* __restrict__ bl,
    float* __restrict__ out, unsigned* __restrict__ flags, unsigned short* __restrict__ hbuf)
{
    const int bid = blockIdx.x;
    const int bg  = bid >> 5;          // 0..3
    const int cg  = bid & 31;          // 0..31
    const int tid = threadIdx.x;
    const int w   = tid >> 6;          // 0..3 = gate type
    const int lane = tid & 63;
    const int nl  = lane & 15;
    const int kq  = lane >> 4;

    __shared__ float gates[4][16][17];

    // ---- Preload B fragments (weights) into registers: K=768 -> 24 k-steps.
    short8 bf[24];
    {
        const int gcol = w * HH + cg * 16 + nl;    // gate col in [0,2048)
        #pragma unroll
        for (int kk = 0; kk < 24; ++kk) {
            short8 v;
            #pragma unroll
            for (int j = 0; j < 8; ++j)
                v[j] = f2bf(wl[(size_t)(kk * 32 + kq * 8 + j) * 2048 + gcol]);
            bf[kk] = v;
        }
    }
    const float bias = bl[w * HH + cg * 16 + nl];

    // Elementwise-phase mapping (thread-local c state).
    const int ebl   = tid >> 4;            // 0..15
    const int ej    = tid & 15;
    const int ebrow = bg * 16 + ebl;
    const int ecol  = cg * 16 + ej;
    float creg = c0[(size_t)ebrow * HH + ecol];

    const int arow = bg * 16 + nl;         // batch row this lane loads for A-frags

    // Per-wave flag: flags[bg*128 + cg*4 + w]. Wave-0 poll: lane L checks the
    // 4 flags of WG (L&31) via one dwordx4.
    unsigned* wFlag = flags + bg * 128 + cg * 4 + w;
    unsigned* pollP = flags + bg * 128 + (lane & 31) * 4;

    const f32x4 zero = {0.f, 0.f, 0.f, 0.f};
    f32x4 acc[4] = {zero, zero, zero, zero};
    xpart(acc, x, arow, 0, kq, bf);        // x-part for t=0

    for (int t = 0; t < TT; ++t) {
        // ---- h part: K=[256,768)
        if (t == 0) {
            const float* hp = h0 + (size_t)arow * HH + kq * 8;
            #pragma unroll
            for (int kk = 0; kk < 16; ++kk) {
                f32x4 lo = *(const f32x4*)(hp + kk * 32);
                f32x4 hi = *(const f32x4*)(hp + kk * 32 + 4);
                acc[kk & 3] = MFMA(pack8(lo, hi), bf[8 + kk], acc[kk & 3]);
            }
        } else {
            const unsigned short* hp = hbuf + ((t - 1) & 1) * (BB * HH) + (size_t)arow * HH + kq * 8;
            short8 ha[16];
            #pragma unroll
            for (int kk = 0; kk < 16; ++kk)
                asm volatile("global_load_dwordx4 %0, %1, off offset:%2 sc0 sc1"
                             : "=&v"(ha[kk]) : "v"(hp), "i"(kk * 64));
            asm volatile("s_waitcnt vmcnt(0)" ::: "memory");
            __builtin_amdgcn_sched_barrier(0);
            #pragma unroll
            for (int kk = 0; kk < 16; ++kk)
                acc[kk & 3] = MFMA(ha[kk], bf[8 + kk], acc[kk & 3]);
        }

        // ---- gate tile -> LDS (C layout: row=kq*4+r, col=nl)
        #pragma unroll
        for (int r = 0; r < 4; ++r)
            gates[w][kq * 4 + r][nl] = acc[0][r] + acc[1][r] + acc[2][r] + acc[3][r] + bias;
        __syncthreads();

        // ---- elementwise (per-thread owns one (b,hcol))
        float iv = gates[0][ebl][ej];
        float gv = gates[1][ebl][ej];
        float fv = gates[2][ebl][ej];
        float ov = gates[3][ebl][ej];
        float fs = sigf(fv + 1.0f);                 // haiku forget bias
        creg = fs * creg + sigf(iv) * tanhfast(gv);
        float hn = sigf(ov) * tanhfast(creg);

        {   // h store (MALL) first, then y (plain)
            unsigned hb = (unsigned)(unsigned short)f2bf(hn);
            unsigned short* hp = hbuf + (t & 1) * (BB * HH) + (size_t)ebrow * HH + ecol;
            asm volatile("global_store_short %0, %1, off sc0 sc1" :: "v"(hp), "v"(hb) : "memory");
            out[((size_t)ebrow * TT + t) * OUTD + ecol] = hn;
        }

        if (t == TT - 1) {
            out[YTOT + (size_t)ebrow * OUTD + ecol] = hn;               // h_fin
            out[YTOT + BB * OUTD + (size_t)ebrow * OUTD + ecol] = creg; // c_fin
        } else {
            // ---- release: this wave's h stores acked at MALL, then its flag.
            asm volatile("s_waitcnt vmcnt(0)" ::: "memory");
            if (lane == 0) {
                unsigned fv2 = (unsigned)(t + 1);
                asm volatile("global_store_dword %0, %1, off sc0 sc1"
                             :: "v"(wFlag), "v"(fv2) : "memory");
            }
            // ---- overlap: x-part for t+1 while peers finish
            acc[0] = zero; acc[1] = zero; acc[2] = zero; acc[3] = zero;
            xpart(acc, x, arow, t + 1, kq, bf);
            // ---- wave 0 polls all 128 flags of this batch-group
            if (tid < 64) {
                const unsigned tgt = (unsigned)(t + 1);
                for (;;) {
                    u32x4 f4;
                    asm volatile("global_load_dwordx4 %0, %1, off sc0 sc1"
                                 : "=&v"(f4) : "v"(pollP));
                    asm volatile("s_waitcnt vmcnt(0)" ::: "memory");
                    int ok = (f4[0] >= tgt) && (f4[1] >= tgt) && (f4[2] >= tgt) && (f4[3] >= tgt);
                    if (__all(ok)) break;
                }
            }
            __syncthreads();
            __builtin_amdgcn_sched_barrier(0);
        }
    }
}

// ---------------------------------------------------------------------------
// w_lin -> Bt (bf16, transposed [n][k]) so B-fragments are contiguous 16B.
// ---------------------------------------------------------------------------
__global__ void conv_wlin(const float* __restrict__ wlin, unsigned short* __restrict__ Bt)
{
    const int g  = blockIdx.x * 256 + threadIdx.x;
    const int n  = g >> 6;
    const int kb = (g & 63) * 8;
    short8 v;
    #pragma unroll
    for (int j = 0; j < 8; ++j) v[j] = f2bf(wlin[(size_t)(kb + j) * OUTD + n]);
    *(short8*)(Bt + (size_t)n * OUTD + kb) = v;
}

// ---------------------------------------------------------------------------
// In-place y = h_hist @ w_lin + b_lin on d_out (32 rows per WG, row-local).
// ---------------------------------------------------------------------------
__global__ __launch_bounds__(256, 2) void out_linear(
    float* __restrict__ out, const unsigned short* __restrict__ Bt, const float* __restrict__ blin)
{
    const int r0  = blockIdx.x * 32;
    const int tid = threadIdx.x;
    const int w = tid >> 6, lane = tid & 63, nl = lane & 15, kq = lane >> 4;

    __shared__ unsigned short aLds[32][520];

    {   // stage 32 rows x 512 fp32 -> bf16 LDS
        const int row = tid >> 3;
        const int cb  = (tid & 7) * 64;
        const float* src = out + (size_t)(r0 + row) * OUTD + cb;
        #pragma unroll
        for (int c = 0; c < 64; c += 4) {
            f32x4 v = *(const f32x4*)(src + c);
            aLds[row][cb + c + 0] = (unsigned short)f2bf(v[0]);
            aLds[row][cb + c + 1] = (unsigned short)f2bf(v[1]);
            aLds[row][cb + c + 2] = (unsigned short)f2bf(v[2]);
            aLds[row][cb + c + 3] = (unsigned short)f2bf(v[3]);
        }
    }
    __syncthreads();

    const f32x4 zero = {0.f, 0.f, 0.f, 0.f};
    f32x4 acc[2][8];
    #pragma unroll
    for (int m = 0; m < 2; ++m)
        #pragma unroll
        for (int n = 0; n < 8; ++n) acc[m][n] = zero;

    #pragma unroll
    for (int kk = 0; kk < 16; ++kk) {
        short8 A0 = *(const short8*)&aLds[nl][kk * 32 + kq * 8];
        short8 A1 = *(const short8*)&aLds[16 + nl][kk * 32 + kq * 8];
        #pragma unroll
        for (int n = 0; n < 8; ++n) {
            const int nt = w * 8 + n;
            short8 Bv = *(const short8*)(Bt + (size_t)(nt * 16 + nl) * OUTD + kk * 32 + kq * 8);
            acc[0][n] = MFMA(A0, Bv, acc[0][n]);
            acc[1][n] = MFMA(A1, Bv, acc[1][n]);
        }
    }

    #pragma unroll
    for (int mt = 0; mt < 2; ++mt)
        #pragma unroll
        for (int n = 0; n < 8; ++n) {
            const int col = (w * 8 + n) * 16 + nl;
            const float bb = blin[col];
            #pragma unroll
            for (int r = 0; r < 4; ++r)
                out[(size_t)(r0 + mt * 16 + kq * 4 + r) * OUTD + col] = acc[mt][n][r] + bb;
        }
}

// ---------------------------------------------------------------------------
extern "C" void kernel_launch(void* const* d_in, const int* in_sizes, int n_in,
                              void* d_out, int out_size, void* d_ws, size_t ws_size,
                              hipStream_t stream)
{
    const float* x    = (const float*)d_in[0];
    const float* h0   = (const float*)d_in[1];
    const float* c0   = (const float*)d_in[2];
    const float* wl   = (const float*)d_in[3];
    const float* bl   = (const float*)d_in[4];
    const float* wlin = (const float*)d_in[5];
    const float* blin = (const float*)d_in[6];
    float* out = (float*)d_out;

    unsigned*       flags = (unsigned*)d_ws;                                    // 2KB used
    unsigned short* hbuf  = (unsigned short*)((char*)d_ws + 4096);              // 128KB double-buffered h
    unsigned short* Bt    = (unsigned short*)((char*)d_ws + 4096 + 2 * BB * HH * 2);

    hipMemsetAsync(d_ws, 0, 4096, stream);                 // zero flags
    conv_wlin<<<128, 256, 0, stream>>>(wlin, Bt);
    lstm_rec<<<128, 256, 0, stream>>>(x, h0, c0, wl, bl, out, flags, hbuf);
    out_linear<<<(BB * TT) / 32, 256, 0, stream>>>(out, Bt, blin);
}

// Round 5
// 4784.170 us; speedup vs baseline: 2.2400x; 1.1839x over previous
//
#include <hip/hip_runtime.h>

// LSTM: B=64, T=1024, IN=256, H=512, gates=2048; then Linear 512->512.
// Inputs (fp32): x, h0, c0, w_lstm[768,2048], b_lstm[2048], w_lin[512,512], b_lin[512]
// Output (fp32): y[64,1024,512] ++ h_fin[64,512] ++ c_fin[64,512]
//
// 128 WGs: 4 batch-groups (16 rows) x 32 col-groups (16 h-cols -> 64 gate cols).
// Sync via SENTINEL POLLING: h values (|h|<1) are exchanged through MALL
// (sc0 sc1); consumers poll the data itself until no element equals the
// sentinel 0x7F7F (bf16 ~3.4e38, unreachable). 4 rotating buffers; each WG
// re-sentinels its slice of buf[(t+2)&3] at step t (safe: all reads of that
// buffer provably completed). No flags, no atomics, no separate h load.

#define BB   64
#define TT   1024
#define DIN  256
#define HH   512
#define OUTD 512
#define YTOT (BB*TT*OUTD)
#define SENT 0x7F7F7F7Fu

typedef __attribute__((ext_vector_type(4))) float f32x4;
typedef __attribute__((ext_vector_type(2))) float f32x2;
typedef __attribute__((ext_vector_type(4))) unsigned u32x4;
typedef __attribute__((ext_vector_type(8))) short short8;

__device__ inline short f2bf(float f) {
    unsigned u = __float_as_uint(f);
    unsigned r = u + 0x7fffu + ((u >> 16) & 1u);   // RNE
    return (short)(r >> 16);
}
__device__ inline float sigf(float x) { return 1.0f / (1.0f + __expf(-x)); }
__device__ inline float tanhfast(float x) { return 1.0f - 2.0f / (__expf(2.0f * x) + 1.0f); }

__device__ inline short8 pack8(f32x4 lo, f32x4 hi) {
    short8 a;
    a[0] = f2bf(lo[0]); a[1] = f2bf(lo[1]); a[2] = f2bf(lo[2]); a[3] = f2bf(lo[3]);
    a[4] = f2bf(hi[0]); a[5] = f2bf(hi[1]); a[6] = f2bf(hi[2]); a[7] = f2bf(hi[3]);
    return a;
}

#define MFMA(a, b, c) __builtin_amdgcn_mfma_f32_16x16x32_bf16((a), (b), (c), 0, 0, 0)

// x-part of the gate GEMM for one timestep: 8 MFMAs, K=[0,256).
__device__ inline void xpart(f32x4 acc[4], const float* __restrict__ x, int arow, int t, int kq,
                             const short8* bf) {
    const float* xp = x + ((size_t)arow * TT + t) * DIN + kq * 8;
    #pragma unroll
    for (int kk = 0; kk < 8; ++kk) {
        f32x4 lo = *(const f32x4*)(xp + kk * 32);
        f32x4 hi = *(const f32x4*)(xp + kk * 32 + 4);
        acc[kk & 3] = MFMA(pack8(lo, hi), bf[kk], acc[kk & 3]);
    }
}

__global__ __launch_bounds__(256, 1) void lstm_rec(
    const float* __restrict__ x, const float* __restrict__ h0, const float* __restrict__ c0,
    const float* __restrict__ wl, const float* __restrict__ bl,
    float* __restrict__ out, unsigned short* __restrict__ hbuf)
{
    const int bid = blockIdx.x;
    const int bg  = bid >> 5;          // 0..3
    const int cg  = bid & 31;          // 0..31
    const int tid = threadIdx.x;
    const int w   = tid >> 6;          // 0..3 = gate type
    const int lane = tid & 63;
    const int nl  = lane & 15;
    const int kq  = lane >> 4;

    __shared__ float gates[4][16][17];

    // ---- Preload B fragments (weights) into registers: K=768 -> 24 k-steps.
    short8 bf[24];
    {
        const int gcol = w * HH + cg * 16 + nl;    // gate col in [0,2048)
        #pragma unroll
        for (int kk = 0; kk < 24; ++kk) {
            short8 v;
            #pragma unroll
            for (int j = 0; j < 8; ++j)
                v[j] = f2bf(wl[(size_t)(kk * 32 + kq * 8 + j) * 2048 + gcol]);
            bf[kk] = v;
        }
    }
    const float bias = bl[w * HH + cg * 16 + nl];

    // Elementwise mapping: threads 0..127, each owns (row, col-pair).
    const bool ew   = (tid < 128);
    const int ebl   = tid >> 3;            // 0..15 (row) when ew
    const int ej2   = tid & 7;             // col pair 0..7
    const int ebrow = bg * 16 + (ebl & 15);
    const int ecol0 = cg * 16 + ej2 * 2;
    f32x2 creg = {0.f, 0.f};
    if (ew) creg = *(const f32x2*)&c0[(size_t)ebrow * HH + ecol0];

    const int arow = bg * 16 + nl;         // batch row this lane loads for A-frags

    const f32x4 zero = {0.f, 0.f, 0.f, 0.f};
    f32x4 acc[4] = {zero, zero, zero, zero};
    xpart(acc, x, arow, 0, kq, bf);        // x-part for t=0

    for (int t = 0; t < TT; ++t) {
        // ---- h part: K=[256,768)
        if (t == 0) {
            const float* hp = h0 + (size_t)arow * HH + kq * 8;
            #pragma unroll
            for (int kk = 0; kk < 16; ++kk) {
                f32x4 lo = *(const f32x4*)(hp + kk * 32);
                f32x4 hi = *(const f32x4*)(hp + kk * 32 + 4);
                acc[kk & 3] = MFMA(pack8(lo, hi), bf[8 + kk], acc[kk & 3]);
            }
        } else {
            const unsigned short* hp = hbuf + ((t - 1) & 3) * (BB * HH) + (size_t)arow * HH + kq * 8;
            short8 ha[16];
            for (;;) {   // poll: the load IS the sync (and drains our own stores)
                #pragma unroll
                for (int kk = 0; kk < 16; ++kk)
                    asm volatile("global_load_dwordx4 %0, %1, off offset:%2 sc0 sc1"
                                 : "=&v"(ha[kk]) : "v"(hp), "i"(kk * 64));
                asm volatile("s_waitcnt vmcnt(0)" ::: "memory");
                unsigned m = 0xFFFFFFFFu;
                #pragma unroll
                for (int kk = 0; kk < 16; ++kk) {
                    u32x4 d = __builtin_bit_cast(u32x4, ha[kk]);
                    unsigned v0 = d[0] ^ SENT, v1 = d[1] ^ SENT, v2 = d[2] ^ SENT, v3 = d[3] ^ SENT;
                    m = v0 < m ? v0 : m;  m = v1 < m ? v1 : m;
                    m = v2 < m ? v2 : m;  m = v3 < m ? v3 : m;
                }
                if (__all(m != 0u)) break;
                __builtin_amdgcn_s_sleep(1);
            }
            __builtin_amdgcn_sched_barrier(0);
            #pragma unroll
            for (int kk = 0; kk < 16; ++kk)
                acc[kk & 3] = MFMA(ha[kk], bf[8 + kk], acc[kk & 3]);
        }

        // ---- gate tile -> LDS (C layout: row=kq*4+r, col=nl)
        #pragma unroll
        for (int r = 0; r < 4; ++r)
            gates[w][kq * 4 + r][nl] = acc[0][r] + acc[1][r] + acc[2][r] + acc[3][r] + bias;
        __syncthreads();

        // ---- elementwise: 2 adjacent cols per thread -> dword-granular h store
        if (ew) {
            float i0 = gates[0][ebl][ej2 * 2],     i1 = gates[0][ebl][ej2 * 2 + 1];
            float g0 = gates[1][ebl][ej2 * 2],     g1 = gates[1][ebl][ej2 * 2 + 1];
            float f0 = gates[2][ebl][ej2 * 2],     f1 = gates[2][ebl][ej2 * 2 + 1];
            float o0 = gates[3][ebl][ej2 * 2],     o1 = gates[3][ebl][ej2 * 2 + 1];
            creg[0] = sigf(f0 + 1.0f) * creg[0] + sigf(i0) * tanhfast(g0);
            creg[1] = sigf(f1 + 1.0f) * creg[1] + sigf(i1) * tanhfast(g1);
            float hn0 = sigf(o0) * tanhfast(creg[0]);
            float hn1 = sigf(o1) * tanhfast(creg[1]);

            if (t == TT - 1) {
                f32x2 hv = {hn0, hn1};
                *(f32x2*)&out[((size_t)ebrow * TT + t) * OUTD + ecol0] = hv;
                *(f32x2*)&out[YTOT + (size_t)ebrow * OUTD + ecol0] = hv;            // h_fin
                *(f32x2*)&out[YTOT + BB * OUTD + (size_t)ebrow * OUTD + ecol0] = creg; // c_fin
            } else {
                unsigned hw = (unsigned)(unsigned short)f2bf(hn0)
                            | ((unsigned)(unsigned short)f2bf(hn1) << 16);
                const size_t slot = (size_t)ebrow * HH + ecol0;
                unsigned short* hp  = hbuf + (t & 3) * (BB * HH) + slot;
                unsigned short* sp  = hbuf + ((t + 2) & 3) * (BB * HH) + slot;
                unsigned sv = SENT;
                // sentinel-reset (buffer reused at t+2) + h publish; both drained
                // by this wave's next poll vmcnt(0) before h(t+1) is published.
                asm volatile("global_store_dword %0, %1, off sc0 sc1" :: "v"(sp), "v"(sv) : "memory");
                asm volatile("global_store_dword %0, %1, off sc0 sc1" :: "v"(hp), "v"(hw) : "memory");
                f32x2 hv = {hn0, hn1};
                *(f32x2*)&out[((size_t)ebrow * TT + t) * OUTD + ecol0] = hv;
            }
        }

        if (t < TT - 1) {
            // overlap: x-part for t+1 while peers' h(t) is in flight
            acc[0] = zero; acc[1] = zero; acc[2] = zero; acc[3] = zero;
            xpart(acc, x, arow, t + 1, kq, bf);
            __syncthreads();   // gates LDS reuse protection
        }
    }
}

// ---------------------------------------------------------------------------
// w_lin -> Bt (bf16, transposed [n][k]) so B-fragments are contiguous 16B.
// ---------------------------------------------------------------------------
__global__ void conv_wlin(const float* __restrict__ wlin, unsigned short* __restrict__ Bt)
{
    const int g  = blockIdx.x * 256 + threadIdx.x;
    const int n  = g >> 6;
    const int kb = (g & 63) * 8;
    short8 v;
    #pragma unroll
    for (int j = 0; j < 8; ++j) v[j] = f2bf(wlin[(size_t)(kb + j) * OUTD + n]);
    *(short8*)(Bt + (size_t)n * OUTD + kb) = v;
}

// ---------------------------------------------------------------------------
// In-place y = h_hist @ w_lin + b_lin on d_out (32 rows per WG, row-local).
// ---------------------------------------------------------------------------
__global__ __launch_bounds__(256, 2) void out_linear(
    float* __restrict__ out, const unsigned short* __restrict__ Bt, const float* __restrict__ blin)
{
    const int r0  = blockIdx.x * 32;
    const int tid = threadIdx.x;
    const int w = tid >> 6, lane = tid & 63, nl = lane & 15, kq = lane >> 4;

    __shared__ unsigned short aLds[32][520];

    {   // stage 32 rows x 512 fp32 -> bf16 LDS
        const int row = tid >> 3;
        const int cb  = (tid & 7) * 64;
        const float* src = out + (size_t)(r0 + row) * OUTD + cb;
        #pragma unroll
        for (int c = 0; c < 64; c += 4) {
            f32x4 v = *(const f32x4*)(src + c);
            aLds[row][cb + c + 0] = (unsigned short)f2bf(v[0]);
            aLds[row][cb + c + 1] = (unsigned short)f2bf(v[1]);
            aLds[row][cb + c + 2] = (unsigned short)f2bf(v[2]);
            aLds[row][cb + c + 3] = (unsigned short)f2bf(v[3]);
        }
    }
    __syncthreads();

    const f32x4 zero = {0.f, 0.f, 0.f, 0.f};
    f32x4 acc[2][8];
    #pragma unroll
    for (int m = 0; m < 2; ++m)
        #pragma unroll
        for (int n = 0; n < 8; ++n) acc[m][n] = zero;

    #pragma unroll
    for (int kk = 0; kk < 16; ++kk) {
        short8 A0 = *(const short8*)&aLds[nl][kk * 32 + kq * 8];
        short8 A1 = *(const short8*)&aLds[16 + nl][kk * 32 + kq * 8];
        #pragma unroll
        for (int n = 0; n < 8; ++n) {
            const int nt = w * 8 + n;
            short8 Bv = *(const short8*)(Bt + (size_t)(nt * 16 + nl) * OUTD + kk * 32 + kq * 8);
            acc[0][n] = MFMA(A0, Bv, acc[0][n]);
            acc[1][n] = MFMA(A1, Bv, acc[1][n]);
        }
    }

    #pragma unroll
    for (int mt = 0; mt < 2; ++mt)
        #pragma unroll
        for (int n = 0; n < 8; ++n) {
            const int col = (w * 8 + n) * 16 + nl;
            const float bb = blin[col];
            #pragma unroll
            for (int r = 0; r < 4; ++r)
                out[(size_t)(r0 + mt * 16 + kq * 4 + r) * OUTD + col] = acc[mt][n][r] + bb;
        }
}

// ---------------------------------------------------------------------------
extern "C" void kernel_launch(void* const* d_in, const int* in_sizes, int n_in,
                              void* d_out, int out_size, void* d_ws, size_t ws_size,
                              hipStream_t stream)
{
    const float* x    = (const float*)d_in[0];
    const float* h0   = (const float*)d_in[1];
    const float* c0   = (const float*)d_in[2];
    const float* wl   = (const float*)d_in[3];
    const float* bl   = (const float*)d_in[4];
    const float* wlin = (const float*)d_in[5];
    const float* blin = (const float*)d_in[6];
    float* out = (float*)d_out;

    unsigned short* hbuf = (unsigned short*)((char*)d_ws + 4096);               // 4 x 64KB h buffers
    unsigned short* Bt   = (unsigned short*)((char*)d_ws + 4096 + 4 * BB * HH * 2);

    hipMemsetAsync(hbuf, 0x7F, 4 * BB * HH * 2, stream);   // pre-fill sentinel
    conv_wlin<<<128, 256, 0, stream>>>(wlin, Bt);
    lstm_rec<<<128, 256, 0, stream>>>(x, h0, c0, wl, bl, out, hbuf);
    out_linear<<<(BB * TT) / 32, 256, 0, stream>>>(out, Bt, blin);
}

// Round 6
// 4556.276 us; speedup vs baseline: 2.3520x; 1.0500x over previous
//
#include <hip/hip_runtime.h>

// LSTM: B=64, T=1024, IN=256, H=512, gates=2048; then Linear 512->512.
// Inputs (fp32): x, h0, c0, w_lstm[768,2048], b_lstm[2048], w_lin[512,512], b_lin[512]
// Output (fp32): y[64,1024,512] ++ h_fin[64,512] ++ c_fin[64,512]
//
// 256 WGs (1/CU): 8 batch-groups (8 rows, bg=bid&7) x 32 col-groups (16 h-cols).
// Recurrence sync via SENTINEL POLLING (data IS the flag; 0x7F7F unreachable
// since |h|<1). FAST path (runtime-verified: each bg-group co-XCD, 8 distinct
// XCDs): h exchange through the XCD-LOCAL L2 (plain stores, sc0 polls).
// FALLBACK (any other placement): MALL (sc0 sc1) — R5-proven, same protocol.
// 4 rotating buffers; each WG re-sentinels its slice of buf[(t+2)&3] at step t.

#define BB   64
#define TT   1024
#define DIN  256
#define HH   512
#define OUTD 512
#define NWG  256
#define YTOT (BB*TT*OUTD)
#define SENT 0x7F7F7F7Fu

typedef __attribute__((ext_vector_type(4))) float f32x4;
typedef __attribute__((ext_vector_type(2))) float f32x2;
typedef __attribute__((ext_vector_type(4))) unsigned u32x4;
typedef __attribute__((ext_vector_type(8))) short short8;

__device__ inline short f2bf(float f) {
    unsigned u = __float_as_uint(f);
    unsigned r = u + 0x7fffu + ((u >> 16) & 1u);   // RNE
    return (short)(r >> 16);
}
__device__ inline float sigf(float x) { return 1.0f / (1.0f + __expf(-x)); }
__device__ inline float tanhfast(float x) { return 1.0f - 2.0f / (__expf(2.0f * x) + 1.0f); }

__device__ inline short8 pack8(f32x4 lo, f32x4 hi) {
    short8 a;
    a[0] = f2bf(lo[0]); a[1] = f2bf(lo[1]); a[2] = f2bf(lo[2]); a[3] = f2bf(lo[3]);
    a[4] = f2bf(hi[0]); a[5] = f2bf(hi[1]); a[6] = f2bf(hi[2]); a[7] = f2bf(hi[3]);
    return a;
}

#define MFMA(a, b, c) __builtin_amdgcn_mfma_f32_16x16x32_bf16((a), (b), (c), 0, 0, 0)

// x-part of the gate GEMM for one timestep: 8 MFMAs, K=[0,256).
__device__ inline void xpart(f32x4 acc[4], const float* __restrict__ x, int arow, int t, int kq,
                             const short8* bf) {
    const float* xp = x + ((size_t)arow * TT + t) * DIN + kq * 8;
    #pragma unroll
    for (int kk = 0; kk < 8; ++kk) {
        f32x4 lo = *(const f32x4*)(xp + kk * 32);
        f32x4 hi = *(const f32x4*)(xp + kk * 32 + 4);
        acc[kk & 3] = MFMA(pack8(lo, hi), bf[kk], acc[kk & 3]);
    }
}

template<bool LOCAL>
__device__ inline void lstm_loop(const float* __restrict__ x, const float* __restrict__ h0,
                                 const float* __restrict__ c0, float* __restrict__ out,
                                 unsigned short* __restrict__ hbuf,
                                 const short8* bf, float bias, int bg, int cg,
                                 float (*gates)[16][17])
{
    const int tid  = threadIdx.x;
    const int w    = tid >> 6;
    const int lane = tid & 63;
    const int nl   = lane & 15;
    const int kq   = lane >> 4;

    // Elementwise mapping: threads 0..63 own (row 0..7, col-pair 0..7).
    const bool ew   = (tid < 64);
    const int ebl   = (tid >> 3) & 7;
    const int ej2   = tid & 7;
    const int ebrow = bg * 8 + ebl;
    const int ecol0 = cg * 16 + ej2 * 2;
    f32x2 creg = {0.f, 0.f};
    if (ew) creg = *(const f32x2*)&c0[(size_t)ebrow * HH + ecol0];

    const int arow = bg * 8 + (nl & 7);    // A rows 8..15 duplicate 0..7

    const f32x4 zero = {0.f, 0.f, 0.f, 0.f};
    f32x4 acc[4] = {zero, zero, zero, zero};
    xpart(acc, x, arow, 0, kq, bf);        // x-part for t=0

    for (int t = 0; t < TT; ++t) {
        // ---- h part: K=[256,768)
        if (t == 0) {
            const float* hp = h0 + (size_t)arow * HH + kq * 8;
            #pragma unroll
            for (int kk = 0; kk < 16; ++kk) {
                f32x4 lo = *(const f32x4*)(hp + kk * 32);
                f32x4 hi = *(const f32x4*)(hp + kk * 32 + 4);
                acc[kk & 3] = MFMA(pack8(lo, hi), bf[8 + kk], acc[kk & 3]);
            }
        } else {
            const unsigned short* hp = hbuf + ((t - 1) & 3) * (BB * HH) + (size_t)arow * HH + kq * 8;
            short8 ha[16];
            for (;;) {   // poll: the load IS the sync (vmcnt(0) also drains our stores)
                #pragma unroll
                for (int kk = 0; kk < 16; ++kk) {
                    if (LOCAL)
                        asm volatile("global_load_dwordx4 %0, %1, off offset:%2 sc0"
                                     : "=&v"(ha[kk]) : "v"(hp), "i"(kk * 64));
                    else
                        asm volatile("global_load_dwordx4 %0, %1, off offset:%2 sc0 sc1"
                                     : "=&v"(ha[kk]) : "v"(hp), "i"(kk * 64));
                }
                asm volatile("s_waitcnt vmcnt(0)" ::: "memory");
                unsigned m = 0xFFFFFFFFu;
                #pragma unroll
                for (int kk = 0; kk < 16; ++kk) {
                    u32x4 d = __builtin_bit_cast(u32x4, ha[kk]);
                    unsigned v0 = d[0] ^ SENT, v1 = d[1] ^ SENT, v2 = d[2] ^ SENT, v3 = d[3] ^ SENT;
                    m = v0 < m ? v0 : m;  m = v1 < m ? v1 : m;
                    m = v2 < m ? v2 : m;  m = v3 < m ? v3 : m;
                }
                if (__all(m != 0u)) break;
                __builtin_amdgcn_s_sleep(1);
            }
            __builtin_amdgcn_sched_barrier(0);
            #pragma unroll
            for (int kk = 0; kk < 16; ++kk)
                acc[kk & 3] = MFMA(ha[kk], bf[8 + kk], acc[kk & 3]);
        }

        // ---- gate tile -> LDS (C layout: row=kq*4+r, col=nl; rows 8-15 dup)
        #pragma unroll
        for (int r = 0; r < 4; ++r)
            gates[w][kq * 4 + r][nl] = acc[0][r] + acc[1][r] + acc[2][r] + acc[3][r] + bias;
        __syncthreads();

        // ---- elementwise: 2 adjacent cols per thread -> dword-granular h store
        if (ew) {
            float i0 = gates[0][ebl][ej2 * 2], i1 = gates[0][ebl][ej2 * 2 + 1];
            float g0 = gates[1][ebl][ej2 * 2], g1 = gates[1][ebl][ej2 * 2 + 1];
            float f0 = gates[2][ebl][ej2 * 2], f1 = gates[2][ebl][ej2 * 2 + 1];
            float o0 = gates[3][ebl][ej2 * 2], o1 = gates[3][ebl][ej2 * 2 + 1];
            creg[0] = sigf(f0 + 1.0f) * creg[0] + sigf(i0) * tanhfast(g0);
            creg[1] = sigf(f1 + 1.0f) * creg[1] + sigf(i1) * tanhfast(g1);
            float hn0 = sigf(o0) * tanhfast(creg[0]);
            float hn1 = sigf(o1) * tanhfast(creg[1]);

            if (t == TT - 1) {
                f32x2 hv = {hn0, hn1};
                *(f32x2*)&out[((size_t)ebrow * TT + t) * OUTD + ecol0] = hv;
                *(f32x2*)&out[YTOT + (size_t)ebrow * OUTD + ecol0] = hv;               // h_fin
                *(f32x2*)&out[YTOT + BB * OUTD + (size_t)ebrow * OUTD + ecol0] = creg; // c_fin
            } else {
                unsigned hw = (unsigned)(unsigned short)f2bf(hn0)
                            | ((unsigned)(unsigned short)f2bf(hn1) << 16);
                const size_t slot = (size_t)ebrow * HH + ecol0;
                unsigned short* hp = hbuf + (t & 3) * (BB * HH) + slot;
                unsigned short* sp = hbuf + ((t + 2) & 3) * (BB * HH) + slot;
                unsigned sv = SENT;
                // sentinel-reset (buffer reused at t+2) then h publish; both are
                // drained by this wave's next poll vmcnt(0) before h(t+1) exists.
                if (LOCAL) {
                    asm volatile("global_store_dword %0, %1, off" :: "v"(sp), "v"(sv) : "memory");
                    asm volatile("global_store_dword %0, %1, off" :: "v"(hp), "v"(hw) : "memory");
                } else {
                    asm volatile("global_store_dword %0, %1, off sc0 sc1" :: "v"(sp), "v"(sv) : "memory");
                    asm volatile("global_store_dword %0, %1, off sc0 sc1" :: "v"(hp), "v"(hw) : "memory");
                }
                f32x2 hv = {hn0, hn1};
                *(f32x2*)&out[((size_t)ebrow * TT + t) * OUTD + ecol0] = hv;
            }
        }

        if (t < TT - 1) {
            // overlap: x-part for t+1 while peers' h(t) is in flight
            acc[0] = zero; acc[1] = zero; acc[2] = zero; acc[3] = zero;
            xpart(acc, x, arow, t + 1, kq, bf);
            __syncthreads();   // gates LDS reuse protection
        }
    }
}

__global__ __launch_bounds__(256, 1) void lstm_rec(
    const float* __restrict__ x, const float* __restrict__ h0, const float* __restrict__ c0,
    const float* __restrict__ wl, const float* __restrict__ bl,
    float* __restrict__ out, unsigned* __restrict__ xccArr, unsigned short* __restrict__ hbuf)
{
    const int bid = blockIdx.x;
    const int tid = threadIdx.x;
    const int w   = tid >> 6;
    const int nl  = tid & 15;
    const int kq  = (tid & 63) >> 4;
    const int bg  = bid & 7;           // batch group (8 rows)
    const int cg  = bid >> 3;          // col group (16 h-cols)

    __shared__ float gates[4][16][17];
    __shared__ int vals[NWG];
    __shared__ int okS;

    // ---- placement discovery: publish XCC via MALL-sentinel (no atomics) ----
    unsigned xcc;
    asm volatile("s_getreg_b32 %0, hwreg(20, 0, 4)" : "=s"(xcc));   // HW_REG_XCC_ID
    if (tid == 0) {
        okS = 1;
        unsigned pv = (xcc & 15u) + 1u;            // nonzero publication
        unsigned* p = xccArr + bid;
        asm volatile("global_store_dword %0, %1, off sc0 sc1" :: "v"(p), "v"(pv) : "memory");
    }
    {   // each thread polls one WG's entry (all 256 WGs co-resident: 1 WG/CU)
        unsigned v;
        unsigned* p = xccArr + tid;
        for (;;) {
            asm volatile("global_load_dword %0, %1, off sc0 sc1" : "=&v"(v) : "v"(p));
            asm volatile("s_waitcnt vmcnt(0)" ::: "memory");
            if (v != 0u) break;
            __builtin_amdgcn_s_sleep(8);
        }
        vals[tid] = (int)(v - 1u);
    }
    __syncthreads();
    if (vals[tid] != vals[tid & 7]) atomicAnd(&okS, 0);   // group must be XCD-uniform
    if (tid < 8) {                                        // 8 groups on 8 distinct XCDs
        #pragma unroll
        for (int j = 0; j < 8; ++j)
            if (j != tid && vals[j] == vals[tid]) atomicAnd(&okS, 0);
    }
    __syncthreads();
    const bool fast = (okS != 0);

    // ---- weight slice -> registers (24 x short8 per lane) ----
    short8 bf[24];
    {
        const int gcol = w * HH + cg * 16 + nl;
        #pragma unroll
        for (int kk = 0; kk < 24; ++kk) {
            short8 v;
            #pragma unroll
            for (int j = 0; j < 8; ++j)
                v[j] = f2bf(wl[(size_t)(kk * 32 + kq * 8 + j) * 2048 + gcol]);
            bf[kk] = v;
        }
    }
    const float bias = bl[w * HH + cg * 16 + nl];

    if (fast) lstm_loop<true >(x, h0, c0, out, hbuf, bf, bias, bg, cg, gates);
    else      lstm_loop<false>(x, h0, c0, out, hbuf, bf, bias, bg, cg, gates);
}

// ---------------------------------------------------------------------------
// w_lin -> Bt (bf16, transposed [n][k]) so B-fragments are contiguous 16B.
// ---------------------------------------------------------------------------
__global__ void conv_wlin(const float* __restrict__ wlin, unsigned short* __restrict__ Bt)
{
    const int g  = blockIdx.x * 256 + threadIdx.x;
    const int n  = g >> 6;
    const int kb = (g & 63) * 8;
    short8 v;
    #pragma unroll
    for (int j = 0; j < 8; ++j) v[j] = f2bf(wlin[(size_t)(kb + j) * OUTD + n]);
    *(short8*)(Bt + (size_t)n * OUTD + kb) = v;
}

// ---------------------------------------------------------------------------
// In-place y = h_hist @ w_lin + b_lin on d_out (32 rows per WG, row-local).
// ---------------------------------------------------------------------------
__global__ __launch_bounds__(256, 2) void out_linear(
    float* __restrict__ out, const unsigned short* __restrict__ Bt, const float* __restrict__ blin)
{
    const int r0  = blockIdx.x * 32;
    const int tid = threadIdx.x;
    const int w = tid >> 6, lane = tid & 63, nl = lane & 15, kq = lane >> 4;

    __shared__ unsigned short aLds[32][520];

    {   // stage 32 rows x 512 fp32 -> bf16 LDS
        const int row = tid >> 3;
        const int cb  = (tid & 7) * 64;
        const float* src = out + (size_t)(r0 + row) * OUTD + cb;
        #pragma unroll
        for (int c = 0; c < 64; c += 4) {
            f32x4 v = *(const f32x4*)(src + c);
            aLds[row][cb + c + 0] = (unsigned short)f2bf(v[0]);
            aLds[row][cb + c + 1] = (unsigned short)f2bf(v[1]);
            aLds[row][cb + c + 2] = (unsigned short)f2bf(v[2]);
            aLds[row][cb + c + 3] = (unsigned short)f2bf(v[3]);
        }
    }
    __syncthreads();

    const f32x4 zero = {0.f, 0.f, 0.f, 0.f};
    f32x4 acc[2][8];
    #pragma unroll
    for (int m = 0; m < 2; ++m)
        #pragma unroll
        for (int n = 0; n < 8; ++n) acc[m][n] = zero;

    #pragma unroll
    for (int kk = 0; kk < 16; ++kk) {
        short8 A0 = *(const short8*)&aLds[nl][kk * 32 + kq * 8];
        short8 A1 = *(const short8*)&aLds[16 + nl][kk * 32 + kq * 8];
        #pragma unroll
        for (int n = 0; n < 8; ++n) {
            const int nt = w * 8 + n;
            short8 Bv = *(const short8*)(Bt + (size_t)(nt * 16 + nl) * OUTD + kk * 32 + kq * 8);
            acc[0][n] = MFMA(A0, Bv, acc[0][n]);
            acc[1][n] = MFMA(A1, Bv, acc[1][n]);
        }
    }

    #pragma unroll
    for (int mt = 0; mt < 2; ++mt)
        #pragma unroll
        for (int n = 0; n < 8; ++n) {
            const int col = (w * 8 + n) * 16 + nl;
            const float bb = blin[col];
            #pragma unroll
            for (int r = 0; r < 4; ++r)
                out[(size_t)(r0 + mt * 16 + kq * 4 + r) * OUTD + col] = acc[mt][n][r] + bb;
        }
}

// ---------------------------------------------------------------------------
extern "C" void kernel_launch(void* const* d_in, const int* in_sizes, int n_in,
                              void* d_out, int out_size, void* d_ws, size_t ws_size,
                              hipStream_t stream)
{
    const float* x    = (const float*)d_in[0];
    const float* h0   = (const float*)d_in[1];
    const float* c0   = (const float*)d_in[2];
    const float* wl   = (const float*)d_in[3];
    const float* bl   = (const float*)d_in[4];
    const float* wlin = (const float*)d_in[5];
    const float* blin = (const float*)d_in[6];
    float* out = (float*)d_out;

    unsigned*       xccArr = (unsigned*)d_ws;                                   // 1KB used
    unsigned short* hbuf   = (unsigned short*)((char*)d_ws + 4096);             // 4 x 64KB h buffers
    unsigned short* Bt     = (unsigned short*)((char*)d_ws + 4096 + 4 * BB * HH * 2);

    hipMemsetAsync(d_ws, 0, 4096, stream);                 // zero xccArr
    hipMemsetAsync(hbuf, 0x7F, 4 * BB * HH * 2, stream);   // pre-fill sentinel
    conv_wlin<<<128, 256, 0, stream>>>(wlin, Bt);
    lstm_rec<<<NWG, 256, 0, stream>>>(x, h0, c0, wl, bl, out, xccArr, hbuf);
    out_linear<<<(BB * TT) / 32, 256, 0, stream>>>(out, Bt, blin);
}